// Round 10
// baseline (173.819 us; speedup 1.0000x reference)
//
#include <hip/hip_runtime.h>

// Balloon-Windkessel BOLD, explicit Euler, T=1000, B=16384.
// alpha==1 decouples the system: (s,f) is an affine scan with constant 2x2
// matrix A; v,q are affine scans given f; only E(f) is nonlinear.
//
// ROUND-10: 3 BARRIER-FREE PASSES, FULL-CHIP GEOMETRY, INLINE PREFIXES.
// r9's k_walk proved the serial-walk shape but ran 16384 threads = 256
// waves = 1/4 of the 1024 SIMDs (75% idle) and spilled its z arrays
// (VGPR=52). Fix the geometry, not the shape: CHUNKS=8 x CL=125 gives
// 131072 threads per pass (2048 waves = 2/SIMD everywhere). Cross-chunk
// coupling = inline f64 prefix folds (<=7 steps, block-uniform, no
// divergence) -- NO standalone scan kernels, NO barriers, NO LDS anywhere.
//   k_aggsf: (s,f) chunk aggregates -> ws (1 MB). 64 MB cold read.
//   k_vq   : inline f64 (s,f) prefix -> fp32 start; replay 125 steps
//            (z L3-hot), accumulate v,q chunk aggregates -> ws (1 MB).
//   k_emit : both prefixes inline (f64, av^125); replay 125 steps,
//            compute y, NT full-line stores. 64 MB write.
// Numerics: within-chunk fp32 ops token-identical to the validated r0-r7
// chain; f trajectory in k_vq/k_emit bitwise identical (identical f64
// prefix ops -> identical fp32 start -> identical ops). v,q recurrence
// has damping time-constant ~30 steps, so Rv/Rq fp32 rounding saturates
// (does not grow with CL). Fallback: proven r0 monolith if ws too small.

#define BATCH     16384
#define DT        0.01f
#define NOISE_AMP 0.01f
#define V0        0.02f
#define CHUNKS    8
#define CL        125         // 8 * 125 = 1000 steps
#define TPB       256

#if __has_builtin(__builtin_amdgcn_exp2f)
#define EXP2F(x) __builtin_amdgcn_exp2f(x)
#else
#define EXP2F(x) exp2f(x)
#endif

__device__ __forceinline__ float uf(float x) {
    return __uint_as_float(__builtin_amdgcn_readfirstlane(__float_as_uint(x)));
}

struct D22 { double a, b, c, d; };
__device__ __forceinline__ D22 dmul(D22 x, D22 y) {
    D22 r;
    r.a = x.a * y.a + x.b * y.c;  r.b = x.a * y.b + x.b * y.d;
    r.c = x.c * y.a + x.d * y.c;  r.d = x.c * y.b + x.d * y.d;
    return r;
}

// A^125 in f64 (125 = 64+32+16+8+4+1)
__device__ __forceinline__ D22 a125_of(float sigma, float mu) {
    D22 A; A.a = 1.0 - 0.01 * (double)sigma; A.b = -0.01 * (double)mu;
           A.c = 0.01;                       A.d = 1.0;
    D22 A2 = dmul(A, A), A4 = dmul(A2, A2), A8 = dmul(A4, A4);
    D22 A16 = dmul(A8, A8), A32 = dmul(A16, A16), A64 = dmul(A32, A32);
    return dmul(dmul(dmul(dmul(dmul(A64, A32), A16), A8), A4), A);
}

__device__ __forceinline__ double av125_of(float lamb) {
    const double avd = 1.0 - 0.01 / (double)lamb;
    const double av2 = avd * avd, av4 = av2 * av2, av8 = av4 * av4;
    const double av16 = av8 * av8, av32 = av16 * av16, av64 = av32 * av32;
    return av64 * av32 * av16 * av8 * av4 * avd;    // av^125
}

// ---------------------------------------------------------------------------
// k_aggsf: per-(chunk,sim) fp32 (s,f) chunk aggregate. (form validated r0-r7)
// ---------------------------------------------------------------------------
__global__ __launch_bounds__(TPB, 4) void k_aggsf(
    const float* __restrict__ noise,
    const float* __restrict__ p_sigma,
    const float* __restrict__ p_mu,
    float* __restrict__ wsRS, float* __restrict__ wsRF)
{
    const int sim = blockIdx.x * TPB + threadIdx.x;
    const int cc  = blockIdx.y;

    const float sigma = uf(p_sigma[0]);
    const float mu    = uf(p_mu[0]);
    const float as_   = 1.0f - DT * sigma;
    const float dtn   = DT * NOISE_AMP;
    const float dtm   = DT * mu;

    const float* zp = noise + (size_t)cc * (CL * BATCH) + sim;
    float rs = 0.0f, rf = 0.0f;
#pragma unroll 25
    for (int j = 0; j < CL; ++j) {
        const float z = zp[(size_t)j * BATCH];
        const float u = __builtin_fmaf(dtn, z, dtm);
        const float t = __builtin_fmaf(as_, rs, __builtin_fmaf(-dtm, rf, u));
        rf = __builtin_fmaf(DT, rs, rf);
        rs = t;
    }
    wsRS[cc * BATCH + sim] = rs;
    wsRF[cc * BATCH + sim] = rf;
}

// ---------------------------------------------------------------------------
// k_vq: inline f64 (s,f) prefix; replay f; fp32 v,q chunk aggregates.
// ---------------------------------------------------------------------------
__global__ __launch_bounds__(TPB, 4) void k_vq(
    const float* __restrict__ noise,
    const float* __restrict__ p_sigma,
    const float* __restrict__ p_mu,
    const float* __restrict__ p_lamb,
    const float* __restrict__ p_beta,
    const float* __restrict__ wsRS, const float* __restrict__ wsRF,
    float* __restrict__ wsRV, float* __restrict__ wsRQ)
{
    const int sim = blockIdx.x * TPB + threadIdx.x;
    const int cc  = blockIdx.y;

    const float sigma = uf(p_sigma[0]);
    const float mu    = uf(p_mu[0]);
    const float lamb  = uf(p_lamb[0]);
    const float beta  = uf(p_beta[0]);

    const float as_   = 1.0f - DT * sigma;
    const float dtn   = DT * NOISE_AMP;
    const float dtm   = DT * mu;
    const float dt_il = uf((float)(0.01 / (double)lamb));
    const float av    = 1.0f - dt_il;
    const float kq    = uf(dt_il / beta);
    const float lc    = uf(log2f(1.0f - beta));

    // inline f64 (s,f) prefix over chunks < cc (block-uniform trip count)
    const D22 P = a125_of(sigma, mu);
    double sd = 0.0, fd = 1.0;
    for (int k = 0; k < cc; ++k) {
        const double rs = (double)wsRS[k * BATCH + sim];
        const double rf = (double)wsRF[k * BATCH + sim];
        const double ns = P.a * sd + P.b * fd + rs;
        fd              = P.c * sd + P.d * fd + rf;
        sd = ns;
    }
    float s = (float)sd, f = (float)fd;

    const float* zp = noise + (size_t)cc * (CL * BATCH) + sim;
    float Rv = 0.0f, Rq = 0.0f;
#pragma unroll 25
    for (int j = 0; j < CL; ++j) {
        const float z    = zp[(size_t)j * BATCH];
        const float invf = __builtin_amdgcn_rcpf(f);
        const float e2   = EXP2F(lc * invf);
        const float t1   = __builtin_fmaf(-f, e2, f);       // f*E(f)
        Rv = __builtin_fmaf(av, Rv, dt_il * f);
        Rq = __builtin_fmaf(av, Rq, kq * t1);
        // canonical (s,f) step — MUST match k_emit exactly
        const float s2 = __builtin_fmaf(as_, s,
                         __builtin_fmaf(dtn, z,
                         __builtin_fmaf(-dtm, f, dtm)));
        f = __builtin_fmaf(DT, s, f);
        s = s2;
    }
    wsRV[cc * BATCH + sim] = Rv;
    wsRQ[cc * BATCH + sim] = Rq;
}

// ---------------------------------------------------------------------------
// k_emit: both inline prefixes; replay; compute y; NT store.
// ---------------------------------------------------------------------------
__global__ __launch_bounds__(TPB, 4) void k_emit(
    const float* __restrict__ noise,
    const float* __restrict__ p_sigma,
    const float* __restrict__ p_mu,
    const float* __restrict__ p_lamb,
    const float* __restrict__ p_beta,
    const float* __restrict__ p_psi,
    const float* __restrict__ p_phi,
    const float* __restrict__ p_chi,
    const float* __restrict__ wsRS, const float* __restrict__ wsRF,
    const float* __restrict__ wsRV, const float* __restrict__ wsRQ,
    float* __restrict__ out)
{
    const int sim = blockIdx.x * TPB + threadIdx.x;
    const int cc  = blockIdx.y;

    const float sigma = uf(p_sigma[0]);
    const float mu    = uf(p_mu[0]);
    const float lamb  = uf(p_lamb[0]);
    const float beta  = uf(p_beta[0]);
    const float psi   = uf(p_psi[0]);
    const float phi   = uf(p_phi[0]);
    const float chi   = uf(p_chi[0]);

    const float as_   = 1.0f - DT * sigma;
    const float dtn   = DT * NOISE_AMP;
    const float dtm   = DT * mu;
    const float dt_il = uf((float)(0.01 / (double)lamb));
    const float av    = 1.0f - dt_il;
    const float kq    = uf(dt_il / beta);
    const float lc    = uf(log2f(1.0f - beta));
    const float c0 = V0 * (phi + psi + chi), c1 = V0 * phi, c2 = V0 * psi, c3 = V0 * chi;

    // inline f64 (s,f) prefix — ops IDENTICAL to k_vq (same fp32 start)
    const D22 P = a125_of(sigma, mu);
    double sd = 0.0, fd = 1.0;
    for (int k = 0; k < cc; ++k) {
        const double rs = (double)wsRS[k * BATCH + sim];
        const double rf = (double)wsRF[k * BATCH + sim];
        const double ns = P.a * sd + P.b * fd + rs;
        fd              = P.c * sd + P.d * fd + rf;
        sd = ns;
    }
    float s = (float)sd, f = (float)fd;

    // inline f64 v,q prefix (scalar weight av^125)
    const double ap = av125_of(lamb);
    double vd = 1.0, qd = 1.0;
    for (int k = 0; k < cc; ++k) {
        vd = ap * vd + (double)wsRV[k * BATCH + sim];
        qd = ap * qd + (double)wsRQ[k * BATCH + sim];
    }
    float v = (float)vd, q = (float)qd;

    const float* zp = noise + (size_t)cc * (CL * BATCH) + sim;
    float*       op = out   + (size_t)cc * (CL * BATCH) + sim;

#pragma unroll 25
    for (int j = 0; j < CL; ++j) {
        const float z    = zp[(size_t)j * BATCH];
        const float invf = __builtin_amdgcn_rcpf(f);
        const float e2   = EXP2F(lc * invf);
        const float t1   = __builtin_fmaf(-f, e2, f);
        const float vn   = __builtin_fmaf(av, v, dt_il * f);
        const float qn   = __builtin_fmaf(av, q, kq * t1);
        // canonical (s,f) step — identical to k_vq
        const float s2 = __builtin_fmaf(as_, s,
                         __builtin_fmaf(dtn, z,
                         __builtin_fmaf(-dtm, f, dtm)));
        f = __builtin_fmaf(DT, s, f);
        s = s2;

        const float invv = __builtin_amdgcn_rcpf(vn);
        const float y = __builtin_fmaf(-c2, qn * invv,
                        __builtin_fmaf(-c3, vn,
                        __builtin_fmaf(-c1, qn, c0)));
        __builtin_nontemporal_store(y, op + (size_t)j * BATCH);
        v = vn; q = qn;
    }
}

// ---------------------------------------------------------------------------
// Fallback: proven round-0 monolithic kernel (47us/dispatch).
// ---------------------------------------------------------------------------
#define CH0   20
#define CL0   50
#define GS0   32
#define NT0   (CH0 * GS0)   // 640

__global__ __launch_bounds__(NT0, 5) void balloon_mono(
    const float* __restrict__ noise,
    const float* __restrict__ p_sigma,
    const float* __restrict__ p_mu,
    const float* __restrict__ p_lamb,
    const float* __restrict__ p_beta,
    const float* __restrict__ p_psi,
    const float* __restrict__ p_phi,
    const float* __restrict__ p_chi,
    float* __restrict__ out)
{
    const int tid = threadIdx.x;
    const int g   = tid & (GS0 - 1);
    const int cc  = tid >> 5;
    const int sim = blockIdx.x * GS0 + g;

    const float sigma = uf(p_sigma[0]);
    const float mu    = uf(p_mu[0]);
    const float lamb  = uf(p_lamb[0]);
    const float beta  = uf(p_beta[0]);
    const float psi   = uf(p_psi[0]);
    const float phi   = uf(p_phi[0]);
    const float chi   = uf(p_chi[0]);

    const float as_   = 1.0f - DT * sigma;
    const float dtn   = DT * NOISE_AMP;
    const float dtm   = DT * mu;
    const float dt_il = uf((float)(0.01 / (double)lamb));
    const float av    = 1.0f - dt_il;
    const float kq    = uf(dt_il / beta);
    const float lc    = uf(log2f(1.0f - beta));
    const float c0 = V0 * (phi + psi + chi), c1 = V0 * phi, c2 = V0 * psi, c3 = V0 * chi;

    D22 A; A.a = 1.0 - 0.01 * (double)sigma; A.b = -0.01 * (double)mu;
           A.c = 0.01;                       A.d = 1.0;
    D22 A2 = dmul(A, A), A4 = dmul(A2, A2), A8 = dmul(A4, A4);
    D22 A16 = dmul(A8, A8), A32 = dmul(A16, A16);
    D22 P = dmul(dmul(A32, A16), A2);               // A^50
    double avd = 1.0 - 0.01 / (double)lamb;
    double av2 = avd * avd, av4 = av2 * av2, av8 = av4 * av4;
    double av16 = av8 * av8, av32 = av16 * av16;
    double ap = av32 * av16 * av2;                  // av^50

    float M11[5], M12[5], M21[5], M22[5], AVP[5];
#pragma unroll
    for (int j = 0; j < 5; ++j) {
        M11[j] = uf((float)P.a); M12[j] = uf((float)P.b);
        M21[j] = uf((float)P.c); M22[j] = uf((float)P.d);
        AVP[j] = uf((float)ap);
        P = dmul(P, P); ap = ap * ap;
    }

    float ws_h = 0.0f, wf_h = 1.0f, avc = 1.0f;
#pragma unroll
    for (int j = 0; j < 5; ++j) {
        if ((cc >> j) & 1) {
            float t = __builtin_fmaf(M11[j], ws_h, M12[j] * wf_h);
            wf_h = __builtin_fmaf(M21[j], ws_h, M22[j] * wf_h);
            ws_h = t;
            avc *= AVP[j];
        }
    }

    __shared__ float sA[NT0];
    __shared__ float sB[NT0];

    const float* zp = noise + cc * (CL0 * BATCH) + sim;

    float rs = 0.0f, rf = 0.0f;
#pragma unroll 10
    for (int j = 0; j < CL0; ++j) {
        const float z = zp[j * BATCH];
        const float u = __builtin_fmaf(dtn, z, dtm);
        const float t = __builtin_fmaf(as_, rs, __builtin_fmaf(-dtm, rf, u));
        rf = __builtin_fmaf(DT, rs, rf);
        rs = t;
    }

    sA[tid] = rs; sB[tid] = rf;
    __syncthreads();
#pragma unroll
    for (int j = 0; j < 5; ++j) {
        const int off = 1 << j;
        float ns = 0.0f, nf = 0.0f;
        const bool has = (cc >= off);
        if (has) { ns = sA[tid - off * GS0]; nf = sB[tid - off * GS0]; }
        __syncthreads();
        if (has) {
            rs = __builtin_fmaf(M11[j], ns, __builtin_fmaf(M12[j], nf, rs));
            rf = __builtin_fmaf(M21[j], ns, __builtin_fmaf(M22[j], nf, rf));
            sA[tid] = rs; sB[tid] = rf;
        }
        __syncthreads();
    }
    float s0 = ws_h, f0 = wf_h;
    if (cc > 0) { s0 += sA[tid - GS0]; f0 += sB[tid - GS0]; }
    __syncthreads();

    float s = s0, f = f0, Rv = 0.0f, Rq = 0.0f;
#pragma unroll 10
    for (int j = 0; j < CL0; ++j) {
        const float z    = zp[j * BATCH];
        const float invf = __builtin_amdgcn_rcpf(f);
        const float e2   = EXP2F(lc * invf);
        const float t1   = __builtin_fmaf(-f, e2, f);
        Rv = __builtin_fmaf(av, Rv, dt_il * f);
        Rq = __builtin_fmaf(av, Rq, kq * t1);
        const float s2 = __builtin_fmaf(as_, s,
                         __builtin_fmaf(dtn, z,
                         __builtin_fmaf(-dtm, f, dtm)));
        f = __builtin_fmaf(DT, s, f);
        s = s2;
    }

    sA[tid] = Rv; sB[tid] = Rq;
    __syncthreads();
#pragma unroll
    for (int j = 0; j < 5; ++j) {
        const int off = 1 << j;
        float nv = 0.0f, nq = 0.0f;
        const bool has = (cc >= off);
        if (has) { nv = sA[tid - off * GS0]; nq = sB[tid - off * GS0]; }
        __syncthreads();
        if (has) {
            Rv = __builtin_fmaf(AVP[j], nv, Rv);
            Rq = __builtin_fmaf(AVP[j], nq, Rq);
            sA[tid] = Rv; sB[tid] = Rq;
        }
        __syncthreads();
    }
    float v = avc, q = avc;
    if (cc > 0) { v += sA[tid - GS0]; q += sB[tid - GS0]; }

    s = s0; f = f0;
    float* op = out + cc * (CL0 * BATCH) + sim;
#pragma unroll 10
    for (int j = 0; j < CL0; ++j) {
        const float z    = zp[j * BATCH];
        const float invf = __builtin_amdgcn_rcpf(f);
        const float e2   = EXP2F(lc * invf);
        const float t1   = __builtin_fmaf(-f, e2, f);
        const float vn   = __builtin_fmaf(av, v, dt_il * f);
        const float qn   = __builtin_fmaf(av, q, kq * t1);
        const float s2 = __builtin_fmaf(as_, s,
                         __builtin_fmaf(dtn, z,
                         __builtin_fmaf(-dtm, f, dtm)));
        f = __builtin_fmaf(DT, s, f);
        s = s2;

        const float invv = __builtin_amdgcn_rcpf(vn);
        const float y = __builtin_fmaf(-c2, qn * invv,
                        __builtin_fmaf(-c3, vn,
                        __builtin_fmaf(-c1, qn, c0)));
        op[j * BATCH] = y;
        v = vn; q = qn;
    }
}

extern "C" void kernel_launch(void* const* d_in, const int* in_sizes, int n_in,
                              void* d_out, int out_size, void* d_ws, size_t ws_size,
                              hipStream_t stream) {
    const float* noise   = (const float*)d_in[0];
    const float* p_sigma = (const float*)d_in[1];
    const float* p_mu    = (const float*)d_in[2];
    const float* p_lamb  = (const float*)d_in[3];
    const float* p_beta  = (const float*)d_in[4];
    const float* p_psi   = (const float*)d_in[5];
    const float* p_phi   = (const float*)d_in[6];
    const float* p_chi   = (const float*)d_in[7];

    const size_t narr = (size_t)CHUNKS * BATCH;            // 131072 floats
    const size_t need = 4 * narr * sizeof(float);          // 2.1 MB
    if (d_ws != nullptr && ws_size >= need) {
        float* wsRS = (float*)d_ws;
        float* wsRF = wsRS + narr;
        float* wsRV = wsRF + narr;
        float* wsRQ = wsRV + narr;

        const dim3 g(BATCH / TPB, CHUNKS);                 // (64, 8) = 512 blocks
        k_aggsf<<<g, TPB, 0, stream>>>(noise, p_sigma, p_mu, wsRS, wsRF);
        k_vq<<<g, TPB, 0, stream>>>(noise, p_sigma, p_mu, p_lamb, p_beta,
                                    wsRS, wsRF, wsRV, wsRQ);
        k_emit<<<g, TPB, 0, stream>>>(noise, p_sigma, p_mu, p_lamb, p_beta,
                                      p_psi, p_phi, p_chi,
                                      wsRS, wsRF, wsRV, wsRQ, (float*)d_out);
    } else {
        balloon_mono<<<BATCH / GS0, NT0, 0, stream>>>(
            noise, p_sigma, p_mu, p_lamb, p_beta, p_psi, p_phi, p_chi,
            (float*)d_out);
    }
}

// Round 11
// 151.888 us; speedup vs baseline: 1.1444x; 1.1444x over previous
//
#include <hip/hip_runtime.h>

// Balloon-Windkessel BOLD, explicit Euler, T=1000, B=16384.
// alpha==1 decouples the system: (s,f) is an affine scan with constant 2x2
// matrix A; v,q are affine scans given f; only E(f) is nonlinear.
//
// ROUND-11: FINE-GRAINED 5-KERNEL PIPELINE (r7 numerics, fixed geometry).
// Evidence r10: the agg passes at CHUNKS=8 cost ~11us combined, but emit
// at 512 blocks (8 waves/CU) took 47us. r6 measured the SAME emit loop at
// 2560 blocks (32 waves/CU) in ~7us -> occupancy is THE lever for these
// barrier-free serial walkers. So: CHUNKS=40 x CL=25 for ALL z-passes
// (655360 threads, 8 blocks/CU, 32 waves/CU), and standalone f64 scan
// kernels (r7-validated ops) with one fix: BATCH-LOAD all 80 aggregates
// into registers before the serial 40-step recurrence (one latency
// exposure instead of 40; launch_bounds(64,1) gives the VGPR room - r9
// lesson: defaults spill big register arrays).
//   k_aggsf : (s,f) chunk aggregates -> ws        (64 MB cold rd, ~10us)
//   k_scansf: per-sim f64 affine scan, batched    (5 MB,          ~2us)
//   k_aggvq : replay f, v,q chunk aggregates      (64 MB L3-hot,  ~8us)
//   k_scanvq: per-sim f64 scalar scan, batched    (5 MB,          ~2us)
//   k_emit  : replay f, compute y, NT store       (64 MB wr,     ~11us)
// Numerics: token-identical to r7's passing run (absmax 9.536743e-07).
// Fallback: proven r0 monolith if ws too small.

#define BATCH     16384
#define DT        0.01f
#define NOISE_AMP 0.01f
#define V0        0.02f
#define CHUNKS    40
#define CL        25          // 40 * 25 = 1000 steps
#define TPB       256         // streaming-pass block size
#define STPB      64          // scan-kernel block size

#if __has_builtin(__builtin_amdgcn_exp2f)
#define EXP2F(x) __builtin_amdgcn_exp2f(x)
#else
#define EXP2F(x) exp2f(x)
#endif

__device__ __forceinline__ float uf(float x) {
    return __uint_as_float(__builtin_amdgcn_readfirstlane(__float_as_uint(x)));
}

struct D22 { double a, b, c, d; };
__device__ __forceinline__ D22 dmul(D22 x, D22 y) {
    D22 r;
    r.a = x.a * y.a + x.b * y.c;  r.b = x.a * y.b + x.b * y.d;
    r.c = x.c * y.a + x.d * y.c;  r.d = x.c * y.b + x.d * y.d;
    return r;
}

__device__ __forceinline__ D22 a25_of(float sigma, float mu) {
    D22 A; A.a = 1.0 - 0.01 * (double)sigma; A.b = -0.01 * (double)mu;
           A.c = 0.01;                       A.d = 1.0;
    D22 A2 = dmul(A, A), A4 = dmul(A2, A2), A8 = dmul(A4, A4);
    D22 A16 = dmul(A8, A8);
    return dmul(dmul(A16, A8), A);                  // A^25
}

// ---------------------------------------------------------------------------
// k_aggsf: per-(chunk,sim) fp32 (s,f) chunk aggregate. (validated r7)
// ---------------------------------------------------------------------------
__global__ __launch_bounds__(TPB, 8) void k_aggsf(
    const float* __restrict__ noise,
    const float* __restrict__ p_sigma,
    const float* __restrict__ p_mu,
    float* __restrict__ wsS, float* __restrict__ wsF)
{
    const int sim = blockIdx.x * TPB + threadIdx.x;
    const int cc  = blockIdx.y;

    const float sigma = uf(p_sigma[0]);
    const float mu    = uf(p_mu[0]);
    const float as_   = 1.0f - DT * sigma;
    const float dtn   = DT * NOISE_AMP;
    const float dtm   = DT * mu;

    const float* zp = noise + (size_t)cc * (CL * BATCH) + sim;
    float rs = 0.0f, rf = 0.0f;
#pragma unroll
    for (int j = 0; j < CL; ++j) {
        const float z = zp[(size_t)j * BATCH];
        const float u = __builtin_fmaf(dtn, z, dtm);
        const float t = __builtin_fmaf(as_, rs, __builtin_fmaf(-dtm, rf, u));
        rf = __builtin_fmaf(DT, rs, rf);
        rs = t;
    }
    wsS[cc * BATCH + sim] = rs;
    wsF[cc * BATCH + sim] = rf;
}

// ---------------------------------------------------------------------------
// k_scansf: per-sim serial f64 affine scan (batched loads); aggregates ->
// chunk-START states. Ops identical to r7's validated k_scansf.
// ---------------------------------------------------------------------------
__global__ __launch_bounds__(STPB, 1) void k_scansf(
    const float* __restrict__ p_sigma,
    const float* __restrict__ p_mu,
    float* __restrict__ wsS, float* __restrict__ wsF)
{
    const int sim = blockIdx.x * STPB + threadIdx.x;
    const D22 P = a25_of(uf(p_sigma[0]), uf(p_mu[0]));

    // batch-load ALL aggregates first: one latency exposure, 80 regs
    float rs[CHUNKS], rf[CHUNKS];
#pragma unroll
    for (int c = 0; c < CHUNKS; ++c) {
        rs[c] = wsS[c * BATCH + sim];
        rf[c] = wsF[c * BATCH + sim];
    }

    double s = 0.0, f = 1.0;   // state at t=0
#pragma unroll
    for (int c = 0; c < CHUNKS; ++c) {
        wsS[c * BATCH + sim] = (float)s;
        wsF[c * BATCH + sim] = (float)f;
        const double ns = P.a * s + P.b * f + (double)rs[c];
        f               = P.c * s + P.d * f + (double)rf[c];
        s = ns;
    }
}

// ---------------------------------------------------------------------------
// k_aggvq: replay f from fp32 (s0,f0); fp32 v,q chunk aggregates. (r7)
// ---------------------------------------------------------------------------
__global__ __launch_bounds__(TPB, 8) void k_aggvq(
    const float* __restrict__ noise,
    const float* __restrict__ p_sigma,
    const float* __restrict__ p_mu,
    const float* __restrict__ p_lamb,
    const float* __restrict__ p_beta,
    const float* __restrict__ wsS, const float* __restrict__ wsF,
    float* __restrict__ wsV, float* __restrict__ wsQ)
{
    const int sim = blockIdx.x * TPB + threadIdx.x;
    const int cc  = blockIdx.y;

    const float sigma = uf(p_sigma[0]);
    const float mu    = uf(p_mu[0]);
    const float lamb  = uf(p_lamb[0]);
    const float beta  = uf(p_beta[0]);

    const float as_   = 1.0f - DT * sigma;
    const float dtn   = DT * NOISE_AMP;
    const float dtm   = DT * mu;
    const float dt_il = uf((float)(0.01 / (double)lamb));
    const float av    = 1.0f - dt_il;
    const float kq    = uf(dt_il / beta);
    const float lc    = uf(log2f(1.0f - beta));

    float s = wsS[cc * BATCH + sim];
    float f = wsF[cc * BATCH + sim];

    const float* zp = noise + (size_t)cc * (CL * BATCH) + sim;
    float Rv = 0.0f, Rq = 0.0f;
#pragma unroll
    for (int j = 0; j < CL; ++j) {
        const float z    = zp[(size_t)j * BATCH];
        const float invf = __builtin_amdgcn_rcpf(f);
        const float e2   = EXP2F(lc * invf);
        const float t1   = __builtin_fmaf(-f, e2, f);       // f*E(f)
        Rv = __builtin_fmaf(av, Rv, dt_il * f);
        Rq = __builtin_fmaf(av, Rq, kq * t1);
        // canonical (s,f) step — MUST match k_emit exactly
        const float s2 = __builtin_fmaf(as_, s,
                         __builtin_fmaf(dtn, z,
                         __builtin_fmaf(-dtm, f, dtm)));
        f = __builtin_fmaf(DT, s, f);
        s = s2;
    }
    wsV[cc * BATCH + sim] = Rv;
    wsQ[cc * BATCH + sim] = Rq;
}

// ---------------------------------------------------------------------------
// k_scanvq: per-sim serial f64 scalar scan (batched loads). (r7 ops)
// ---------------------------------------------------------------------------
__global__ __launch_bounds__(STPB, 1) void k_scanvq(
    const float* __restrict__ p_lamb,
    float* __restrict__ wsV, float* __restrict__ wsQ)
{
    const int sim = blockIdx.x * STPB + threadIdx.x;
    const double avd = 1.0 - 0.01 / (double)uf(p_lamb[0]);
    const double av2 = avd * avd, av4 = av2 * av2, av8 = av4 * av4;
    const double av16 = av8 * av8;
    const double ap = av16 * av8 * avd;                 // av^25

    float Rv[CHUNKS], Rq[CHUNKS];
#pragma unroll
    for (int c = 0; c < CHUNKS; ++c) {
        Rv[c] = wsV[c * BATCH + sim];
        Rq[c] = wsQ[c * BATCH + sim];
    }

    double v = 1.0, q = 1.0;   // state at t=0
#pragma unroll
    for (int c = 0; c < CHUNKS; ++c) {
        wsV[c * BATCH + sim] = (float)v;
        wsQ[c * BATCH + sim] = (float)q;
        v = ap * v + (double)Rv[c];
        q = ap * q + (double)Rq[c];
    }
}

// ---------------------------------------------------------------------------
// k_emit: replay f, compute y, NT store. (r6-proven ~7us shape; r7 ops)
// ---------------------------------------------------------------------------
__global__ __launch_bounds__(TPB, 8) void k_emit(
    const float* __restrict__ noise,
    const float* __restrict__ p_sigma,
    const float* __restrict__ p_mu,
    const float* __restrict__ p_lamb,
    const float* __restrict__ p_beta,
    const float* __restrict__ p_psi,
    const float* __restrict__ p_phi,
    const float* __restrict__ p_chi,
    const float* __restrict__ wsS, const float* __restrict__ wsF,
    const float* __restrict__ wsV, const float* __restrict__ wsQ,
    float* __restrict__ out)
{
    const int sim = blockIdx.x * TPB + threadIdx.x;
    const int cc  = blockIdx.y;

    const float sigma = uf(p_sigma[0]);
    const float mu    = uf(p_mu[0]);
    const float lamb  = uf(p_lamb[0]);
    const float beta  = uf(p_beta[0]);
    const float psi   = uf(p_psi[0]);
    const float phi   = uf(p_phi[0]);
    const float chi   = uf(p_chi[0]);

    const float as_   = 1.0f - DT * sigma;
    const float dtn   = DT * NOISE_AMP;
    const float dtm   = DT * mu;
    const float dt_il = uf((float)(0.01 / (double)lamb));
    const float av    = 1.0f - dt_il;
    const float kq    = uf(dt_il / beta);
    const float lc    = uf(log2f(1.0f - beta));
    const float c0 = V0 * (phi + psi + chi), c1 = V0 * phi, c2 = V0 * psi, c3 = V0 * chi;

    float s = wsS[cc * BATCH + sim];
    float f = wsF[cc * BATCH + sim];
    float v = wsV[cc * BATCH + sim];
    float q = wsQ[cc * BATCH + sim];

    const float* zp = noise + (size_t)cc * (CL * BATCH) + sim;
    float*       op = out   + (size_t)cc * (CL * BATCH) + sim;

#pragma unroll
    for (int j = 0; j < CL; ++j) {
        const float z    = zp[(size_t)j * BATCH];
        const float invf = __builtin_amdgcn_rcpf(f);
        const float e2   = EXP2F(lc * invf);
        const float t1   = __builtin_fmaf(-f, e2, f);
        const float vn   = __builtin_fmaf(av, v, dt_il * f);
        const float qn   = __builtin_fmaf(av, q, kq * t1);
        // canonical (s,f) step — identical to k_aggvq
        const float s2 = __builtin_fmaf(as_, s,
                         __builtin_fmaf(dtn, z,
                         __builtin_fmaf(-dtm, f, dtm)));
        f = __builtin_fmaf(DT, s, f);
        s = s2;

        const float invv = __builtin_amdgcn_rcpf(vn);
        const float y = __builtin_fmaf(-c2, qn * invv,
                        __builtin_fmaf(-c3, vn,
                        __builtin_fmaf(-c1, qn, c0)));
        __builtin_nontemporal_store(y, op + (size_t)j * BATCH);
        v = vn; q = qn;
    }
}

// ---------------------------------------------------------------------------
// Fallback: proven round-0 monolithic kernel (47us/dispatch).
// ---------------------------------------------------------------------------
#define CH0   20
#define CL0   50
#define GS0   32
#define NT0   (CH0 * GS0)   // 640

__global__ __launch_bounds__(NT0, 5) void balloon_mono(
    const float* __restrict__ noise,
    const float* __restrict__ p_sigma,
    const float* __restrict__ p_mu,
    const float* __restrict__ p_lamb,
    const float* __restrict__ p_beta,
    const float* __restrict__ p_psi,
    const float* __restrict__ p_phi,
    const float* __restrict__ p_chi,
    float* __restrict__ out)
{
    const int tid = threadIdx.x;
    const int g   = tid & (GS0 - 1);
    const int cc  = tid >> 5;
    const int sim = blockIdx.x * GS0 + g;

    const float sigma = uf(p_sigma[0]);
    const float mu    = uf(p_mu[0]);
    const float lamb  = uf(p_lamb[0]);
    const float beta  = uf(p_beta[0]);
    const float psi   = uf(p_psi[0]);
    const float phi   = uf(p_phi[0]);
    const float chi   = uf(p_chi[0]);

    const float as_   = 1.0f - DT * sigma;
    const float dtn   = DT * NOISE_AMP;
    const float dtm   = DT * mu;
    const float dt_il = uf((float)(0.01 / (double)lamb));
    const float av    = 1.0f - dt_il;
    const float kq    = uf(dt_il / beta);
    const float lc    = uf(log2f(1.0f - beta));
    const float c0 = V0 * (phi + psi + chi), c1 = V0 * phi, c2 = V0 * psi, c3 = V0 * chi;

    D22 A; A.a = 1.0 - 0.01 * (double)sigma; A.b = -0.01 * (double)mu;
           A.c = 0.01;                       A.d = 1.0;
    D22 A2 = dmul(A, A), A4 = dmul(A2, A2), A8 = dmul(A4, A4);
    D22 A16 = dmul(A8, A8), A32 = dmul(A16, A16);
    D22 P = dmul(dmul(A32, A16), A2);               // A^50
    double avd = 1.0 - 0.01 / (double)lamb;
    double av2 = avd * avd, av4 = av2 * av2, av8 = av4 * av4;
    double av16 = av8 * av8, av32 = av16 * av16;
    double ap = av32 * av16 * av2;                  // av^50

    float M11[5], M12[5], M21[5], M22[5], AVP[5];
#pragma unroll
    for (int j = 0; j < 5; ++j) {
        M11[j] = uf((float)P.a); M12[j] = uf((float)P.b);
        M21[j] = uf((float)P.c); M22[j] = uf((float)P.d);
        AVP[j] = uf((float)ap);
        P = dmul(P, P); ap = ap * ap;
    }

    float ws_h = 0.0f, wf_h = 1.0f, avc = 1.0f;
#pragma unroll
    for (int j = 0; j < 5; ++j) {
        if ((cc >> j) & 1) {
            float t = __builtin_fmaf(M11[j], ws_h, M12[j] * wf_h);
            wf_h = __builtin_fmaf(M21[j], ws_h, M22[j] * wf_h);
            ws_h = t;
            avc *= AVP[j];
        }
    }

    __shared__ float sA[NT0];
    __shared__ float sB[NT0];

    const float* zp = noise + cc * (CL0 * BATCH) + sim;

    float rs = 0.0f, rf = 0.0f;
#pragma unroll 10
    for (int j = 0; j < CL0; ++j) {
        const float z = zp[j * BATCH];
        const float u = __builtin_fmaf(dtn, z, dtm);
        const float t = __builtin_fmaf(as_, rs, __builtin_fmaf(-dtm, rf, u));
        rf = __builtin_fmaf(DT, rs, rf);
        rs = t;
    }

    sA[tid] = rs; sB[tid] = rf;
    __syncthreads();
#pragma unroll
    for (int j = 0; j < 5; ++j) {
        const int off = 1 << j;
        float ns = 0.0f, nf = 0.0f;
        const bool has = (cc >= off);
        if (has) { ns = sA[tid - off * GS0]; nf = sB[tid - off * GS0]; }
        __syncthreads();
        if (has) {
            rs = __builtin_fmaf(M11[j], ns, __builtin_fmaf(M12[j], nf, rs));
            rf = __builtin_fmaf(M21[j], ns, __builtin_fmaf(M22[j], nf, rf));
            sA[tid] = rs; sB[tid] = rf;
        }
        __syncthreads();
    }
    float s0 = ws_h, f0 = wf_h;
    if (cc > 0) { s0 += sA[tid - GS0]; f0 += sB[tid - GS0]; }
    __syncthreads();

    float s = s0, f = f0, Rv = 0.0f, Rq = 0.0f;
#pragma unroll 10
    for (int j = 0; j < CL0; ++j) {
        const float z    = zp[j * BATCH];
        const float invf = __builtin_amdgcn_rcpf(f);
        const float e2   = EXP2F(lc * invf);
        const float t1   = __builtin_fmaf(-f, e2, f);
        Rv = __builtin_fmaf(av, Rv, dt_il * f);
        Rq = __builtin_fmaf(av, Rq, kq * t1);
        const float s2 = __builtin_fmaf(as_, s,
                         __builtin_fmaf(dtn, z,
                         __builtin_fmaf(-dtm, f, dtm)));
        f = __builtin_fmaf(DT, s, f);
        s = s2;
    }

    sA[tid] = Rv; sB[tid] = Rq;
    __syncthreads();
#pragma unroll
    for (int j = 0; j < 5; ++j) {
        const int off = 1 << j;
        float nv = 0.0f, nq = 0.0f;
        const bool has = (cc >= off);
        if (has) { nv = sA[tid - off * GS0]; nq = sB[tid - off * GS0]; }
        __syncthreads();
        if (has) {
            Rv = __builtin_fmaf(AVP[j], nv, Rv);
            Rq = __builtin_fmaf(AVP[j], nq, Rq);
            sA[tid] = Rv; sB[tid] = Rq;
        }
        __syncthreads();
    }
    float v = avc, q = avc;
    if (cc > 0) { v += sA[tid - GS0]; q += sB[tid - GS0]; }

    s = s0; f = f0;
    float* op = out + cc * (CL0 * BATCH) + sim;
#pragma unroll 10
    for (int j = 0; j < CL0; ++j) {
        const float z    = zp[j * BATCH];
        const float invf = __builtin_amdgcn_rcpf(f);
        const float e2   = EXP2F(lc * invf);
        const float t1   = __builtin_fmaf(-f, e2, f);
        const float vn   = __builtin_fmaf(av, v, dt_il * f);
        const float qn   = __builtin_fmaf(av, q, kq * t1);
        const float s2 = __builtin_fmaf(as_, s,
                         __builtin_fmaf(dtn, z,
                         __builtin_fmaf(-dtm, f, dtm)));
        f = __builtin_fmaf(DT, s, f);
        s = s2;

        const float invv = __builtin_amdgcn_rcpf(vn);
        const float y = __builtin_fmaf(-c2, qn * invv,
                        __builtin_fmaf(-c3, vn,
                        __builtin_fmaf(-c1, qn, c0)));
        op[j * BATCH] = y;
        v = vn; q = qn;
    }
}

extern "C" void kernel_launch(void* const* d_in, const int* in_sizes, int n_in,
                              void* d_out, int out_size, void* d_ws, size_t ws_size,
                              hipStream_t stream) {
    const float* noise   = (const float*)d_in[0];
    const float* p_sigma = (const float*)d_in[1];
    const float* p_mu    = (const float*)d_in[2];
    const float* p_lamb  = (const float*)d_in[3];
    const float* p_beta  = (const float*)d_in[4];
    const float* p_psi   = (const float*)d_in[5];
    const float* p_phi   = (const float*)d_in[6];
    const float* p_chi   = (const float*)d_in[7];

    const size_t narr = (size_t)CHUNKS * BATCH;            // 655360 floats
    const size_t need = 4 * narr * sizeof(float);          // 10.5 MB
    if (d_ws != nullptr && ws_size >= need) {
        float* wsS = (float*)d_ws;
        float* wsF = wsS + narr;
        float* wsV = wsF + narr;
        float* wsQ = wsV + narr;

        const dim3 gStream(BATCH / TPB, CHUNKS);           // (64,40) = 2560 blocks
        const int  gScan = BATCH / STPB;                   // 256 blocks

        k_aggsf<<<gStream, TPB, 0, stream>>>(noise, p_sigma, p_mu, wsS, wsF);
        k_scansf<<<gScan, STPB, 0, stream>>>(p_sigma, p_mu, wsS, wsF);
        k_aggvq<<<gStream, TPB, 0, stream>>>(noise, p_sigma, p_mu, p_lamb, p_beta,
                                             wsS, wsF, wsV, wsQ);
        k_scanvq<<<gScan, STPB, 0, stream>>>(p_lamb, wsV, wsQ);
        k_emit<<<gStream, TPB, 0, stream>>>(noise, p_sigma, p_mu, p_lamb, p_beta,
                                            p_psi, p_phi, p_chi,
                                            wsS, wsF, wsV, wsQ, (float*)d_out);
    } else {
        balloon_mono<<<BATCH / GS0, NT0, 0, stream>>>(
            noise, p_sigma, p_mu, p_lamb, p_beta, p_psi, p_phi, p_chi,
            (float*)d_out);
    }
}